// Round 3
// baseline (336.902 us; speedup 1.0000x reference)
//
#include <hip/hip_runtime.h>
#include <hip/hip_bf16.h>
#include <stdint.h>

typedef __attribute__((ext_vector_type(4))) float f32x4;
typedef __attribute__((ext_vector_type(8))) short s16x8;

__device__ __forceinline__ short f2bf(float f) {
  union { float f; uint32_t u; } v; v.f = f;
  uint32_t r = v.u + 0x7FFFu + ((v.u >> 16) & 1u);
  return (short)(r >> 16);
}
__device__ __forceinline__ uint32_t pack2bf(float a, float b) {
  return (uint32_t)(uint16_t)f2bf(a) | ((uint32_t)(uint16_t)f2bf(b) << 16);
}

__device__ __forceinline__ void async16(const void* g, void* l) {
  __builtin_amdgcn_global_load_lds(
      (const __attribute__((address_space(1))) void*)g,
      (__attribute__((address_space(3))) void*)l, 16, 0, 0);
}

// ---------------- cast x (fp32 -> bf16), 8 elems/thread ----------------
__global__ __launch_bounds__(256) void k_cast_bf16(const float* __restrict__ in,
                                                   short* __restrict__ out, int n8) {
  int i = blockIdx.x * 256 + threadIdx.x;
  if (i >= n8) return;
  const float4* p = (const float4*)in + (size_t)i * 2;
  float4 a = p[0], b = p[1];
  s16x8 o;
  o[0] = f2bf(a.x); o[1] = f2bf(a.y); o[2] = f2bf(a.z); o[3] = f2bf(a.w);
  o[4] = f2bf(b.x); o[5] = f2bf(b.y); o[6] = f2bf(b.z); o[7] = f2bf(b.w);
  ((s16x8*)out)[i] = o;
}

// ---------------- transpose+cast weights: out[n][k] = in[k][n] ----------------
__global__ __launch_bounds__(256) void k_transpose_cast(const float* __restrict__ in,
                                                        short* __restrict__ out,
                                                        int K, int N) {
  int idx = blockIdx.x * 256 + threadIdx.x;
  if (idx >= K * N) return;
  int n = idx / K, k = idx - n * K;
  out[idx] = f2bf(in[(size_t)k * N + n]);
}

// ================= 256x256 8-phase bf16 GEMM (T2+T3+T4+T5) =================
// Swapped-operand MFMA: acc = mfma(B, A) -> lane holds 4 CONSECUTIVE C-cols:
//   C-row = bm*256 + wm*128 + ai*16 + (l&15)
//   C-col = bn*256 + wn*64 + nj*16 + (l>>4)*4 + reg
// -> vectorized epilogue (dwordx2 bf16 / dwordx4 f32), float4 bias.
#define TILE_SH 16384  // 256*64 shorts per matrix tile

template <bool F32OUT>
__global__ __launch_bounds__(512, 2) void k_gemm256(const short* __restrict__ A,
                                                    const short* __restrict__ Bw,
                                                    const float* __restrict__ bias,
                                                    void* __restrict__ C,
                                                    int M, int N, int K, int nbn) {
  __shared__ short lds[2 * 2 * TILE_SH];  // 128 KiB
  const int t = threadIdx.x;
  const int w = t >> 6, l = t & 63;
  const int wm = w >> 2, wn = w & 3;

  const int nwg = gridDim.x;
  const int cpx = nwg >> 3;
  const int wg = ((int)blockIdx.x & 7) * cpx + ((int)blockIdx.x >> 3);
  const int bn = wg % nbn, bm = wg / nbn;

  const int NT = K >> 6;

  auto stage = [&](const short* __restrict__ G, int row0, int kt, short* dst) {
#pragma unroll
    for (int L = 0; L < 2; ++L) {
      int cw = L * 512 + (t & ~63);
      int c = cw + l;
      int r = c >> 3, s = c & 7;
      async16(G + (size_t)(row0 + r) * K + kt + ((s ^ (r & 7)) << 3), dst + cw * 8);
    }
  };
  auto issueA = [&](int Tt, int hf) {
    stage(A, bm * 256 + hf * 128, Tt * 64, lds + (Tt & 1) * 32768 + hf * 8192);
  };
  auto issueB = [&](int Tt, int hf) {
    stage(Bw, bn * 256 + hf * 128, Tt * 64, lds + (Tt & 1) * 32768 + TILE_SH + hf * 8192);
  };

  const int g = l >> 4, v = l & 7;
  int ofsA[2], ofsB[2];
#pragma unroll
  for (int ks = 0; ks < 2; ++ks) {
    ofsA[ks] = (wm * 128 + (l & 15)) * 64 + (((ks * 4 + g) ^ v) << 3);
    ofsB[ks] = (wn * 64 + (l & 15)) * 64 + (((ks * 4 + g) ^ v) << 3);
  }

  f32x4 acc[8][4] = {};
  s16x8 bfr[4][2];

  issueB(0, 0); issueB(0, 1); issueA(0, 0); issueA(0, 1);
  if (NT > 1) { issueB(1, 0); issueB(1, 1); }
  asm volatile("s_waitcnt vmcnt(4)" ::: "memory");
  __builtin_amdgcn_s_barrier();

#define PHASE(AI0, STAGE_STMT, TAIL_STMT)                                                                      \
  {                                                                                                            \
    s16x8 a00 = *(const s16x8*)(Ab + ofsA[0] + (AI0) * 1024);                                                  \
    s16x8 a01 = *(const s16x8*)(Ab + ofsA[1] + (AI0) * 1024);                                                  \
    s16x8 a10 = *(const s16x8*)(Ab + ofsA[0] + ((AI0) + 1) * 1024);                                            \
    s16x8 a11 = *(const s16x8*)(Ab + ofsA[1] + ((AI0) + 1) * 1024);                                            \
    STAGE_STMT;                                                                                                \
    __builtin_amdgcn_s_barrier();                                                                              \
    asm volatile("s_waitcnt lgkmcnt(0)" ::: "memory");                                                         \
    __builtin_amdgcn_s_setprio(1);                                                                             \
    _Pragma("unroll")                                                                                          \
    for (int nj = 0; nj < 4; ++nj) {                                                                           \
      acc[(AI0)][nj] = __builtin_amdgcn_mfma_f32_16x16x32_bf16(bfr[nj][0], a00, acc[(AI0)][nj], 0, 0, 0);      \
      acc[(AI0)][nj] = __builtin_amdgcn_mfma_f32_16x16x32_bf16(bfr[nj][1], a01, acc[(AI0)][nj], 0, 0, 0);      \
      acc[(AI0) + 1][nj] = __builtin_amdgcn_mfma_f32_16x16x32_bf16(bfr[nj][0], a10, acc[(AI0) + 1][nj], 0, 0, 0); \
      acc[(AI0) + 1][nj] = __builtin_amdgcn_mfma_f32_16x16x32_bf16(bfr[nj][1], a11, acc[(AI0) + 1][nj], 0, 0, 0); \
    }                                                                                                          \
    __builtin_amdgcn_s_setprio(0);                                                                             \
    TAIL_STMT;                                                                                                 \
    __builtin_amdgcn_s_barrier();                                                                              \
  }

  for (int T = 0; T < NT; ++T) {
    const short* Ab = lds + (T & 1) * 32768;
    const short* Bb = Ab + TILE_SH;
#pragma unroll
    for (int nj = 0; nj < 4; ++nj)
#pragma unroll
      for (int ks = 0; ks < 2; ++ks)
        bfr[nj][ks] = *(const s16x8*)(Bb + ofsB[ks] + nj * 1024);

    PHASE(0, if (T + 1 < NT) issueA(T + 1, 0), );
    PHASE(2, if (T + 1 < NT) issueA(T + 1, 1), );
    PHASE(4, if (T + 2 < NT) issueB(T + 2, 0), );
    PHASE(6, if (T + 2 < NT) issueB(T + 2, 1),
          if (T + 2 < NT) { asm volatile("s_waitcnt vmcnt(4)" ::: "memory"); }
          else if (T + 1 < NT) { asm volatile("s_waitcnt vmcnt(0)" ::: "memory"); });
  }
#undef PHASE

  // ---- vectorized epilogue: lane holds 4 consecutive cols per frag ----
  const int row_l = bm * 256 + wm * 128 + (l & 15);
  const int col_l = bn * 256 + wn * 64 + (l >> 4) * 4;
#pragma unroll
  for (int ai = 0; ai < 8; ++ai) {
    int row = row_l + ai * 16;
#pragma unroll
    for (int nj = 0; nj < 4; ++nj) {
      int col = col_l + nj * 16;
      float4 bv = *(const float4*)(bias + col);
      f32x4 vv = acc[ai][nj];
      vv[0] += bv.x; vv[1] += bv.y; vv[2] += bv.z; vv[3] += bv.w;
      if (F32OUT) {
        *(float4*)((float*)C + (size_t)row * N + col) = make_float4(vv[0], vv[1], vv[2], vv[3]);
      } else {
        uint2 pk;
        pk.x = pack2bf(vv[0], vv[1]);
        pk.y = pack2bf(vv[2], vv[3]);
        *(uint2*)((short*)C + (size_t)row * N + col) = pk;
      }
    }
  }
}

// ---------------- fused window attention: 1 wave per (b,h) ----------------
__global__ __launch_bounds__(256) void k_attn(const short* __restrict__ qkv,
                                              const float* __restrict__ mask,
                                              const float* __restrict__ bias_table,
                                              short* __restrict__ Y) {
  __shared__ float mask_lds[64 * 64];
  __shared__ float bias_lds[4][128];
  __shared__ short p_lds[4][64][72];

  const int t = threadIdx.x, wv = t >> 6, ln = t & 63;
  const int b = blockIdx.x;
  const int h = blockIdx.y * 4 + wv;

  const float4* mk = (const float4*)(mask + (size_t)(b & 63) * 4096);
#pragma unroll
  for (int u = 0; u < 4; ++u)
    ((float4*)mask_lds)[t + 256 * u] = mk[t + 256 * u];
  for (int u = ln; u < 127; u += 64) bias_lds[wv][u] = bias_table[u * 16 + h];
  __syncthreads();

  const short* qb = qkv + (size_t)b * 64 * 1536 + h * 32;

  s16x8 qf[4], kf[4];
#pragma unroll
  for (int i = 0; i < 4; ++i) {
    qf[i] = *(const s16x8*)(qb + (size_t)(16 * i + (ln & 15)) * 1536 + (ln >> 4) * 8);
    kf[i] = *(const s16x8*)(qb + (size_t)(16 * i + (ln & 15)) * 1536 + 512 + (ln >> 4) * 8);
  }
  f32x4 s[4][4] = {};
#pragma unroll
  for (int i = 0; i < 4; ++i)
#pragma unroll
    for (int j = 0; j < 4; ++j)
      s[i][j] = __builtin_amdgcn_mfma_f32_16x16x32_bf16(qf[i], kf[j], s[i][j], 0, 0, 0);

  const float scale = 0.17677669529663687f;
#pragma unroll
  for (int i = 0; i < 4; ++i)
#pragma unroll
    for (int r = 0; r < 4; ++r) {
      int nn = 16 * i + (ln >> 4) * 4 + r;
      float vals[4];
      float vmax = -1e30f;
#pragma unroll
      for (int j = 0; j < 4; ++j) {
        int mm = 16 * j + (ln & 15);
        float x = s[i][j][r] * scale + bias_lds[wv][nn - mm + 63] + mask_lds[nn * 64 + mm];
        vals[j] = x;
        vmax = fmaxf(vmax, x);
      }
#pragma unroll
      for (int d = 1; d < 16; d <<= 1) vmax = fmaxf(vmax, __shfl_xor(vmax, d, 64));
      float sum = 0.f;
#pragma unroll
      for (int j = 0; j < 4; ++j) {
        float p = __expf(vals[j] - vmax);
        vals[j] = p;
        sum += p;
      }
#pragma unroll
      for (int d = 1; d < 16; d <<= 1) sum += __shfl_xor(sum, d, 64);
      float rsv = 1.0f / sum;
      // pre-scale P by 1/rowsum -> no epilogue rescale needed
#pragma unroll
      for (int j = 0; j < 4; ++j)
        p_lds[wv][nn][16 * j + (ln & 15)] = f2bf(vals[j] * rsv);
    }

  const short* vg = qb + 1024;
  // swapped PV: o[j2][i2] = mfma(vf, pa) -> lane holds d = j2*16+(ln>>4)*4+reg,
  // n = i2*16 + (ln&15)  => 4 consecutive d per lane => packed Y stores
  f32x4 o[2][4] = {};
#pragma unroll
  for (int kk = 0; kk < 2; ++kk) {
    s16x8 pa[4];
#pragma unroll
    for (int i2 = 0; i2 < 4; ++i2)
      pa[i2] = *(const s16x8*)&p_lds[wv][16 * i2 + (ln & 15)][kk * 32 + (ln >> 4) * 8];
#pragma unroll
    for (int j2 = 0; j2 < 2; ++j2) {
      s16x8 vf;
#pragma unroll
      for (int jj = 0; jj < 8; ++jj)
        vf[jj] = vg[(size_t)(kk * 32 + (ln >> 4) * 8 + jj) * 1536 + 16 * j2 + (ln & 15)];
#pragma unroll
      for (int i2 = 0; i2 < 4; ++i2)
        o[j2][i2] = __builtin_amdgcn_mfma_f32_16x16x32_bf16(vf, pa[i2], o[j2][i2], 0, 0, 0);
    }
  }

  // epilogue: Y row = (h*64 + b/16)*64 + (b%16)*4 + i2 ; cc = (ln&15)*32 + j2*16 + (ln>>4)*4
  const int rr = h * 64 + (b >> 4);
#pragma unroll
  for (int i2 = 0; i2 < 4; ++i2) {
    int ss = (b & 15) * 4 + i2;
    short* yrow = Y + ((size_t)rr * 64 + ss) * 512 + (ln & 15) * 32 + (ln >> 4) * 4;
#pragma unroll
    for (int j2 = 0; j2 < 2; ++j2) {
      uint2 pk;
      pk.x = pack2bf(o[j2][i2][0], o[j2][i2][1]);
      pk.y = pack2bf(o[j2][i2][2], o[j2][i2][3]);
      *(uint2*)(yrow + j2 * 16) = pk;
    }
  }
}

extern "C" void kernel_launch(void* const* d_in, const int* in_sizes, int n_in,
                              void* d_out, int out_size, void* d_ws, size_t ws_size,
                              hipStream_t stream) {
  const float* x      = (const float*)d_in[0];
  const float* mask   = (const float*)d_in[1];
  const float* qkv_w  = (const float*)d_in[2];
  const float* qkv_b  = (const float*)d_in[3];
  const float* proj_w = (const float*)d_in[4];
  const float* proj_b = (const float*)d_in[5];
  const float* btab   = (const float*)d_in[6];
  float* out = (float*)d_out;

  char* w = (char*)d_ws;
  short* qkv_ws = (short*)w;                                             // 192 MiB
  short* xbf    = (short*)(w + (size_t)65536 * 1536 * 2);                // 64 MiB
  short* Y      = xbf;                                                   // reuse after GEMM1
  short* wT     = (short*)(w + (size_t)65536 * 1536 * 2 + (size_t)65536 * 512 * 2);
  short* projT  = wT + 1536 * 512;

  k_cast_bf16<<<16384, 256, 0, stream>>>(x, xbf, 33554432 / 8);
  k_transpose_cast<<<(1536 * 512 + 255) / 256, 256, 0, stream>>>(qkv_w, wT, 512, 1536);
  k_transpose_cast<<<(512 * 512 + 255) / 256, 256, 0, stream>>>(proj_w, projT, 512, 512);
  k_gemm256<false><<<1536, 512, 0, stream>>>(xbf, wT, qkv_b, qkv_ws, 65536, 1536, 512, 6);
  k_attn<<<dim3(1024, 4), 256, 0, stream>>>(qkv_ws, mask, btab, Y);
  k_gemm256<true><<<512, 512, 0, stream>>>(Y, projT, proj_b, out, 65536, 512, 512, 2);
}

// Round 4
// 321.954 us; speedup vs baseline: 1.0464x; 1.0464x over previous
//
#include <hip/hip_runtime.h>
#include <hip/hip_bf16.h>
#include <stdint.h>

typedef __attribute__((ext_vector_type(4))) float f32x4;
typedef __attribute__((ext_vector_type(8))) short s16x8;

__device__ __forceinline__ short f2bf(float f) {
  union { float f; uint32_t u; } v; v.f = f;
  uint32_t r = v.u + 0x7FFFu + ((v.u >> 16) & 1u);
  return (short)(r >> 16);
}

__device__ __forceinline__ void async16(const void* g, void* l) {
  __builtin_amdgcn_global_load_lds(
      (const __attribute__((address_space(1))) void*)g,
      (__attribute__((address_space(3))) void*)l, 16, 0, 0);
}

// ---------------- cast x (fp32 -> bf16), 8 elems/thread ----------------
__global__ __launch_bounds__(256) void k_cast_bf16(const float* __restrict__ in,
                                                   short* __restrict__ out, int n8) {
  int i = blockIdx.x * 256 + threadIdx.x;
  if (i >= n8) return;
  const float4* p = (const float4*)in + (size_t)i * 2;
  float4 a = p[0], b = p[1];
  s16x8 o;
  o[0] = f2bf(a.x); o[1] = f2bf(a.y); o[2] = f2bf(a.z); o[3] = f2bf(a.w);
  o[4] = f2bf(b.x); o[5] = f2bf(b.y); o[6] = f2bf(b.z); o[7] = f2bf(b.w);
  ((s16x8*)out)[i] = o;
}

// ---------------- transpose+cast weights: out[n][k] = in[k][n] ----------------
__global__ __launch_bounds__(256) void k_transpose_cast(const float* __restrict__ in,
                                                        short* __restrict__ out,
                                                        int K, int N) {
  int idx = blockIdx.x * 256 + threadIdx.x;
  if (idx >= K * N) return;
  int n = idx / K, k = idx - n * K;
  out[idx] = f2bf(in[(size_t)k * N + n]);
}

// ============ persistent 256x256 8-phase bf16 GEMM (round-2 schedule) ============
// Grid = 256 blocks (1/CU). Block b produces `ntiles` output tiles:
//   tile j: bn = j, bm = (b + j) & 255   (A panel streamed once, B L2-resident)
// Steady schedule continues across tile boundaries (global step s = j*NT + T):
//   ph0/1: issue A(s+1)   ph2/3: issue B(s+2)   tail: vmcnt(4)
// Buffer parity (s&1) and the in-order vmcnt chain are identical to the
// proven single-tile loop. Epilogue stores overlap the next tile's K-loop.
#define TILE_SH 16384  // 256*64 shorts per matrix tile

template <bool F32OUT>
__global__ __launch_bounds__(512, 2) void k_gemm256p(const short* __restrict__ A,
                                                     const short* __restrict__ Bw,
                                                     const float* __restrict__ bias,
                                                     void* __restrict__ C,
                                                     int N, int K, int ntiles) {
  __shared__ short lds[2 * 2 * TILE_SH];  // 128 KiB
  const int t = threadIdx.x;
  const int w = t >> 6, l = t & 63;
  const int wm = w >> 2, wn = w & 3;
  const int b = blockIdx.x;

  const int NT = K >> 6;             // K-tiles per output tile (8 here)
  const int NS = ntiles * NT;        // total steps

  auto stage = [&](const short* __restrict__ G, int row0, int kt, short* dst) {
#pragma unroll
    for (int L = 0; L < 2; ++L) {
      int cw = L * 512 + (t & ~63);
      int c = cw + l;
      int r = c >> 3, s = c & 7;
      async16(G + (size_t)(row0 + r) * K + kt + ((s ^ (r & 7)) << 3), dst + cw * 8);
    }
  };
  // s-step indexed issue: tile = step/NT, ktile = step%NT, buf = step&1
  auto issueA = [&](int step, int hf) {
    int bmv = (b + step / NT) & 255;
    int kt = step % NT;
    stage(A, bmv * 256 + hf * 128, kt * 64, lds + (kt & 1) * 32768 + hf * 8192);
  };
  auto issueB = [&](int step, int hf) {
    int bnv = step / NT;
    int kt = step % NT;
    stage(Bw, bnv * 256 + hf * 128, kt * 64, lds + (kt & 1) * 32768 + TILE_SH + hf * 8192);
  };

  const int g = l >> 4, v = l & 7;
  int ofsA[2], ofsB[2];
#pragma unroll
  for (int ks = 0; ks < 2; ++ks) {
    ofsA[ks] = (wm * 128 + (l & 15)) * 64 + (((ks * 4 + g) ^ v) << 3);
    ofsB[ks] = (wn * 64 + (l & 15)) * 64 + (((ks * 4 + g) ^ v) << 3);
  }

  f32x4 acc[8][4] = {};
  s16x8 bfr[4][2];

  // prologue: A(0), B(0), B(1)
  issueB(0, 0); issueB(0, 1); issueA(0, 0); issueA(0, 1);
  issueB(1, 0); issueB(1, 1);
  asm volatile("s_waitcnt vmcnt(4)" ::: "memory");
  __builtin_amdgcn_s_barrier();

#define PHASE(AI0, STAGE_STMT, TAIL_STMT)                                                                      \
  {                                                                                                            \
    s16x8 a00 = *(const s16x8*)(Ab + ofsA[0] + (AI0) * 1024);                                                  \
    s16x8 a01 = *(const s16x8*)(Ab + ofsA[1] + (AI0) * 1024);                                                  \
    s16x8 a10 = *(const s16x8*)(Ab + ofsA[0] + ((AI0) + 1) * 1024);                                            \
    s16x8 a11 = *(const s16x8*)(Ab + ofsA[1] + ((AI0) + 1) * 1024);                                            \
    STAGE_STMT;                                                                                                \
    __builtin_amdgcn_s_barrier();                                                                              \
    asm volatile("s_waitcnt lgkmcnt(0)" ::: "memory");                                                         \
    __builtin_amdgcn_s_setprio(1);                                                                             \
    _Pragma("unroll")                                                                                          \
    for (int nj = 0; nj < 4; ++nj) {                                                                           \
      acc[(AI0)][nj] = __builtin_amdgcn_mfma_f32_16x16x32_bf16(a00, bfr[nj][0], acc[(AI0)][nj], 0, 0, 0);      \
      acc[(AI0)][nj] = __builtin_amdgcn_mfma_f32_16x16x32_bf16(a01, bfr[nj][1], acc[(AI0)][nj], 0, 0, 0);      \
      acc[(AI0) + 1][nj] = __builtin_amdgcn_mfma_f32_16x16x32_bf16(a10, bfr[nj][0], acc[(AI0) + 1][nj], 0, 0, 0); \
      acc[(AI0) + 1][nj] = __builtin_amdgcn_mfma_f32_16x16x32_bf16(a11, bfr[nj][1], acc[(AI0) + 1][nj], 0, 0, 0); \
    }                                                                                                          \
    __builtin_amdgcn_s_setprio(0);                                                                             \
    TAIL_STMT;                                                                                                 \
    __builtin_amdgcn_s_barrier();                                                                              \
  }

  for (int j = 0; j < ntiles; ++j) {
    for (int T = 0; T < NT; ++T) {
      const int s = j * NT + T;
      const int s1 = s + 1, s2 = s + 2;
      const short* Ab = lds + (T & 1) * 32768;
      const short* Bb = Ab + TILE_SH;
#pragma unroll
      for (int nj = 0; nj < 4; ++nj)
#pragma unroll
        for (int ks = 0; ks < 2; ++ks)
          bfr[nj][ks] = *(const s16x8*)(Bb + ofsB[ks] + nj * 1024);

      PHASE(0, if (s1 < NS) issueA(s1, 0), );
      PHASE(2, if (s1 < NS) issueA(s1, 1), );
      PHASE(4, if (s2 < NS) issueB(s2, 0), );
      PHASE(6, if (s2 < NS) issueB(s2, 1),
            if (s2 < NS) { asm volatile("s_waitcnt vmcnt(4)" ::: "memory"); }
            else if (s1 < NS) { asm volatile("s_waitcnt vmcnt(0)" ::: "memory"); });
    }

    // epilogue for tile j (round-2 scalar form); overlaps next tile's K-loop
    const int bmv = (b + j) & 255;
#pragma unroll
    for (int ai = 0; ai < 8; ++ai)
#pragma unroll
      for (int nj = 0; nj < 4; ++nj) {
        int col = j * 256 + wn * 64 + nj * 16 + (l & 15);
        float bv = bias[col];
#pragma unroll
        for (int r = 0; r < 4; ++r) {
          int row = bmv * 256 + wm * 128 + ai * 16 + (l >> 4) * 4 + r;
          float vv = acc[ai][nj][r] + bv;
          if (F32OUT)
            ((float*)C)[(size_t)row * N + col] = vv;
          else
            ((short*)C)[(size_t)row * N + col] = f2bf(vv);
        }
      }
#pragma unroll
    for (int ai = 0; ai < 8; ++ai)
#pragma unroll
      for (int nj = 0; nj < 4; ++nj)
        acc[ai][nj] = (f32x4){0.f, 0.f, 0.f, 0.f};
  }
#undef PHASE
}

// ---------------- fused window attention: 1 wave per (b,h) ----------------
__global__ __launch_bounds__(256) void k_attn(const short* __restrict__ qkv,
                                              const float* __restrict__ mask,
                                              const float* __restrict__ bias_table,
                                              short* __restrict__ Y) {
  __shared__ float mask_lds[64 * 64];
  __shared__ float bias_lds[4][128];
  __shared__ short p_lds[4][64][72];

  const int t = threadIdx.x, wv = t >> 6, ln = t & 63;
  const int b = blockIdx.x;
  const int h = blockIdx.y * 4 + wv;

  const float4* mk = (const float4*)(mask + (size_t)(b & 63) * 4096);
#pragma unroll
  for (int u = 0; u < 4; ++u)
    ((float4*)mask_lds)[t + 256 * u] = mk[t + 256 * u];
  for (int u = ln; u < 127; u += 64) bias_lds[wv][u] = bias_table[u * 16 + h];
  __syncthreads();

  const short* qb = qkv + (size_t)b * 64 * 1536 + h * 32;

  s16x8 qf[4], kf[4];
#pragma unroll
  for (int i = 0; i < 4; ++i) {
    qf[i] = *(const s16x8*)(qb + (size_t)(16 * i + (ln & 15)) * 1536 + (ln >> 4) * 8);
    kf[i] = *(const s16x8*)(qb + (size_t)(16 * i + (ln & 15)) * 1536 + 512 + (ln >> 4) * 8);
  }
  f32x4 s[4][4] = {};
#pragma unroll
  for (int i = 0; i < 4; ++i)
#pragma unroll
    for (int j = 0; j < 4; ++j)
      s[i][j] = __builtin_amdgcn_mfma_f32_16x16x32_bf16(qf[i], kf[j], s[i][j], 0, 0, 0);

  const float scale = 0.17677669529663687f;
#pragma unroll
  for (int i = 0; i < 4; ++i)
#pragma unroll
    for (int r = 0; r < 4; ++r) {
      int nn = 16 * i + (ln >> 4) * 4 + r;
      float vals[4];
      float vmax = -1e30f;
#pragma unroll
      for (int j = 0; j < 4; ++j) {
        int mm = 16 * j + (ln & 15);
        float x = s[i][j][r] * scale + bias_lds[wv][nn - mm + 63] + mask_lds[nn * 64 + mm];
        vals[j] = x;
        vmax = fmaxf(vmax, x);
      }
#pragma unroll
      for (int d = 1; d < 16; d <<= 1) vmax = fmaxf(vmax, __shfl_xor(vmax, d, 64));
      float sum = 0.f;
#pragma unroll
      for (int j = 0; j < 4; ++j) {
        float p = __expf(vals[j] - vmax);
        vals[j] = p;
        sum += p;
      }
#pragma unroll
      for (int d = 1; d < 16; d <<= 1) sum += __shfl_xor(sum, d, 64);
      float rsv = 1.0f / sum;
      // pre-scale P by 1/rowsum -> no epilogue rescale needed
#pragma unroll
      for (int j = 0; j < 4; ++j)
        p_lds[wv][nn][16 * j + (ln & 15)] = f2bf(vals[j] * rsv);
    }

  const short* vg = qb + 1024;
  f32x4 o[4][2] = {};
#pragma unroll
  for (int kk = 0; kk < 2; ++kk) {
    s16x8 pa[4];
#pragma unroll
    for (int i2 = 0; i2 < 4; ++i2)
      pa[i2] = *(const s16x8*)&p_lds[wv][16 * i2 + (ln & 15)][kk * 32 + (ln >> 4) * 8];
#pragma unroll
    for (int j2 = 0; j2 < 2; ++j2) {
      s16x8 vf;
#pragma unroll
      for (int jj = 0; jj < 8; ++jj)
        vf[jj] = vg[(size_t)(kk * 32 + (ln >> 4) * 8 + jj) * 1536 + 16 * j2 + (ln & 15)];
#pragma unroll
      for (int i2 = 0; i2 < 4; ++i2)
        o[i2][j2] = __builtin_amdgcn_mfma_f32_16x16x32_bf16(pa[i2], vf, o[i2][j2], 0, 0, 0);
    }
  }

#pragma unroll
  for (int i2 = 0; i2 < 4; ++i2)
#pragma unroll
    for (int j2 = 0; j2 < 2; ++j2)
#pragma unroll
      for (int r = 0; r < 4; ++r) {
        int n = 16 * i2 + (ln >> 4) * 4 + r;
        int d = 16 * j2 + (ln & 15);
        int rr = h * 64 + (b >> 4);
        int ss = (b & 15) * 4 + (n >> 4);
        int cc = (n & 15) * 32 + d;
        Y[((size_t)rr * 64 + ss) * 512 + cc] = f2bf(o[i2][j2][r]);
      }
}

extern "C" void kernel_launch(void* const* d_in, const int* in_sizes, int n_in,
                              void* d_out, int out_size, void* d_ws, size_t ws_size,
                              hipStream_t stream) {
  const float* x      = (const float*)d_in[0];
  const float* mask   = (const float*)d_in[1];
  const float* qkv_w  = (const float*)d_in[2];
  const float* qkv_b  = (const float*)d_in[3];
  const float* proj_w = (const float*)d_in[4];
  const float* proj_b = (const float*)d_in[5];
  const float* btab   = (const float*)d_in[6];
  float* out = (float*)d_out;

  char* w = (char*)d_ws;
  short* qkv_ws = (short*)w;                                             // 192 MiB
  short* xbf    = (short*)(w + (size_t)65536 * 1536 * 2);                // 64 MiB
  short* Y      = xbf;                                                   // reuse after GEMM1
  short* wT     = (short*)(w + (size_t)65536 * 1536 * 2 + (size_t)65536 * 512 * 2);
  short* projT  = wT + 1536 * 512;

  k_cast_bf16<<<16384, 256, 0, stream>>>(x, xbf, 33554432 / 8);
  k_transpose_cast<<<(1536 * 512 + 255) / 256, 256, 0, stream>>>(qkv_w, wT, 512, 1536);
  k_transpose_cast<<<(512 * 512 + 255) / 256, 256, 0, stream>>>(proj_w, projT, 512, 512);
  k_gemm256p<false><<<256, 512, 0, stream>>>(xbf, wT, qkv_b, qkv_ws, 1536, 512, 6);
  k_attn<<<dim3(1024, 4), 256, 0, stream>>>(qkv_ws, mask, btab, Y);
  k_gemm256p<true><<<256, 512, 0, stream>>>(Y, projT, proj_b, out, 512, 512, 2);
}

// Round 5
// 316.795 us; speedup vs baseline: 1.0635x; 1.0163x over previous
//
#include <hip/hip_runtime.h>
#include <hip/hip_bf16.h>
#include <stdint.h>

typedef __attribute__((ext_vector_type(4))) float f32x4;
typedef __attribute__((ext_vector_type(8))) short s16x8;

__device__ __forceinline__ short f2bf(float f) {
  union { float f; uint32_t u; } v; v.f = f;
  uint32_t r = v.u + 0x7FFFu + ((v.u >> 16) & 1u);
  return (short)(r >> 16);
}

__device__ __forceinline__ void async16(const void* g, void* l) {
  __builtin_amdgcn_global_load_lds(
      (const __attribute__((address_space(1))) void*)g,
      (__attribute__((address_space(3))) void*)l, 16, 0, 0);
}

// ---------------- cast x (fp32 -> bf16), 8 elems/thread ----------------
__global__ __launch_bounds__(256) void k_cast_bf16(const float* __restrict__ in,
                                                   short* __restrict__ out, int n8) {
  int i = blockIdx.x * 256 + threadIdx.x;
  if (i >= n8) return;
  const float4* p = (const float4*)in + (size_t)i * 2;
  float4 a = p[0], b = p[1];
  s16x8 o;
  o[0] = f2bf(a.x); o[1] = f2bf(a.y); o[2] = f2bf(a.z); o[3] = f2bf(a.w);
  o[4] = f2bf(b.x); o[5] = f2bf(b.y); o[6] = f2bf(b.z); o[7] = f2bf(b.w);
  ((s16x8*)out)[i] = o;
}

// ---------------- transpose+cast weights: out[n][k] = in[k][n] ----------------
__global__ __launch_bounds__(256) void k_transpose_cast(const float* __restrict__ in,
                                                        short* __restrict__ out,
                                                        int K, int N) {
  int idx = blockIdx.x * 256 + threadIdx.x;
  if (idx >= K * N) return;
  int n = idx / K, k = idx - n * K;
  out[idx] = f2bf(in[(size_t)k * N + n]);
}

// ================= 256x256 8-phase bf16 GEMM, A-deep prefetch =================
// Round-2 schedule with prefetch roles SWAPPED for HBM-cold A / L2-hot B:
//   ph0: issue B(T+1,h0)   ph1: issue B(T+1,h1)   (B 2-buffered, L2-hot, 1 ahead)
//   ph2: issue A(T+2,h0)   ph3: issue A(T+2,h1)   (A 3-BUFFERED, HBM-cold, 2 ahead)
//   tail: vmcnt(4) -> A(T+1),B(T+1) landed; A(T+2)x4 stays in flight.
// LDS = 3*32K (A) + 2*32K (B) = 160 KB (gfx950 max).
#define TILE_SH 16384  // 256*64 shorts per tile

template <bool F32OUT>
__global__ __launch_bounds__(512, 1) void k_gemm256(const short* __restrict__ A,
                                                    const short* __restrict__ Bw,
                                                    const float* __restrict__ bias,
                                                    void* __restrict__ C,
                                                    int M, int N, int K, int nbn) {
  __shared__ short lds[5 * TILE_SH];  // 160 KiB: A bufs 0..2, B bufs 3..4
  const int t = threadIdx.x;
  const int w = t >> 6, l = t & 63;
  const int wm = w >> 2, wn = w & 3;

  const int nwg = gridDim.x;
  const int cpx = nwg >> 3;
  const int wg = ((int)blockIdx.x & 7) * cpx + ((int)blockIdx.x >> 3);
  const int bn = wg % nbn, bm = wg / nbn;

  const int NT = K >> 6;  // 8 here

  auto stage = [&](const short* __restrict__ G, int row0, int kt, short* dst) {
#pragma unroll
    for (int L = 0; L < 2; ++L) {
      int cw = L * 512 + (t & ~63);
      int c = cw + l;
      int r = c >> 3, s = c & 7;
      async16(G + (size_t)(row0 + r) * K + kt + ((s ^ (r & 7)) << 3), dst + cw * 8);
    }
  };
  auto issueA = [&](int Tt, int hf) {
    stage(A, bm * 256 + hf * 128, Tt * 64, lds + (Tt % 3) * TILE_SH + hf * 8192);
  };
  auto issueB = [&](int Tt, int hf) {
    stage(Bw, bn * 256 + hf * 128, Tt * 64, lds + (3 + (Tt & 1)) * TILE_SH + hf * 8192);
  };

  const int g = l >> 4, v = l & 7;
  int ofsA[2], ofsB[2];
#pragma unroll
  for (int ks = 0; ks < 2; ++ks) {
    ofsA[ks] = (wm * 128 + (l & 15)) * 64 + (((ks * 4 + g) ^ v) << 3);
    ofsB[ks] = (wn * 64 + (l & 15)) * 64 + (((ks * 4 + g) ^ v) << 3);
  }

  f32x4 acc[8][4] = {};
  s16x8 bfr[4][2];

  // prologue: A(0), B(0), A(1)  -> 12 loads; need A0,B0 -> vmcnt(4)
  issueA(0, 0); issueA(0, 1); issueB(0, 0); issueB(0, 1);
  if (NT > 1) { issueA(1, 0); issueA(1, 1); }
  asm volatile("s_waitcnt vmcnt(4)" ::: "memory");
  __builtin_amdgcn_s_barrier();

#define PHASE(AI0, STAGE_STMT, TAIL_STMT)                                                                      \
  {                                                                                                            \
    s16x8 a00 = *(const s16x8*)(Ab + ofsA[0] + (AI0) * 1024);                                                  \
    s16x8 a01 = *(const s16x8*)(Ab + ofsA[1] + (AI0) * 1024);                                                  \
    s16x8 a10 = *(const s16x8*)(Ab + ofsA[0] + ((AI0) + 1) * 1024);                                            \
    s16x8 a11 = *(const s16x8*)(Ab + ofsA[1] + ((AI0) + 1) * 1024);                                            \
    STAGE_STMT;                                                                                                \
    __builtin_amdgcn_s_barrier();                                                                              \
    asm volatile("s_waitcnt lgkmcnt(0)" ::: "memory");                                                         \
    __builtin_amdgcn_s_setprio(1);                                                                             \
    _Pragma("unroll")                                                                                          \
    for (int nj = 0; nj < 4; ++nj) {                                                                           \
      acc[(AI0)][nj] = __builtin_amdgcn_mfma_f32_16x16x32_bf16(a00, bfr[nj][0], acc[(AI0)][nj], 0, 0, 0);      \
      acc[(AI0)][nj] = __builtin_amdgcn_mfma_f32_16x16x32_bf16(a01, bfr[nj][1], acc[(AI0)][nj], 0, 0, 0);      \
      acc[(AI0) + 1][nj] = __builtin_amdgcn_mfma_f32_16x16x32_bf16(a10, bfr[nj][0], acc[(AI0) + 1][nj], 0, 0, 0); \
      acc[(AI0) + 1][nj] = __builtin_amdgcn_mfma_f32_16x16x32_bf16(a11, bfr[nj][1], acc[(AI0) + 1][nj], 0, 0, 0); \
    }                                                                                                          \
    __builtin_amdgcn_s_setprio(0);                                                                             \
    TAIL_STMT;                                                                                                 \
    __builtin_amdgcn_s_barrier();                                                                              \
  }

  for (int T = 0; T < NT; ++T) {
    const short* Ab = lds + (T % 3) * TILE_SH;
    const short* Bb = lds + (3 + (T & 1)) * TILE_SH;
#pragma unroll
    for (int nj = 0; nj < 4; ++nj)
#pragma unroll
      for (int ks = 0; ks < 2; ++ks)
        bfr[nj][ks] = *(const s16x8*)(Bb + ofsB[ks] + nj * 1024);

    PHASE(0, if (T + 1 < NT) issueB(T + 1, 0), );
    PHASE(2, if (T + 1 < NT) issueB(T + 1, 1), );
    PHASE(4, if (T + 2 < NT) issueA(T + 2, 0), );
    PHASE(6, if (T + 2 < NT) issueA(T + 2, 1),
          if (T + 2 < NT) { asm volatile("s_waitcnt vmcnt(4)" ::: "memory"); }
          else if (T + 1 < NT) { asm volatile("s_waitcnt vmcnt(0)" ::: "memory"); });
  }
#undef PHASE

  // epilogue (round-2 form)
#pragma unroll
  for (int ai = 0; ai < 8; ++ai)
#pragma unroll
    for (int nj = 0; nj < 4; ++nj) {
      int col = bn * 256 + wn * 64 + nj * 16 + (l & 15);
      float bv = bias[col];
#pragma unroll
      for (int r = 0; r < 4; ++r) {
        int row = bm * 256 + wm * 128 + ai * 16 + (l >> 4) * 4 + r;
        float vv = acc[ai][nj][r] + bv;
        if (F32OUT)
          ((float*)C)[(size_t)row * N + col] = vv;
        else
          ((short*)C)[(size_t)row * N + col] = f2bf(vv);
      }
    }
}

// ---------------- fused window attention: 1 wave per (b,h) ----------------
__global__ __launch_bounds__(256) void k_attn(const short* __restrict__ qkv,
                                              const float* __restrict__ mask,
                                              const float* __restrict__ bias_table,
                                              short* __restrict__ Y) {
  __shared__ float mask_lds[64 * 64];
  __shared__ float bias_lds[4][128];
  __shared__ short p_lds[4][64][72];

  const int t = threadIdx.x, wv = t >> 6, ln = t & 63;
  const int b = blockIdx.x;
  const int h = blockIdx.y * 4 + wv;

  const float4* mk = (const float4*)(mask + (size_t)(b & 63) * 4096);
#pragma unroll
  for (int u = 0; u < 4; ++u)
    ((float4*)mask_lds)[t + 256 * u] = mk[t + 256 * u];
  for (int u = ln; u < 127; u += 64) bias_lds[wv][u] = bias_table[u * 16 + h];
  __syncthreads();

  const short* qb = qkv + (size_t)b * 64 * 1536 + h * 32;

  s16x8 qf[4], kf[4];
#pragma unroll
  for (int i = 0; i < 4; ++i) {
    qf[i] = *(const s16x8*)(qb + (size_t)(16 * i + (ln & 15)) * 1536 + (ln >> 4) * 8);
    kf[i] = *(const s16x8*)(qb + (size_t)(16 * i + (ln & 15)) * 1536 + 512 + (ln >> 4) * 8);
  }
  f32x4 s[4][4] = {};
#pragma unroll
  for (int i = 0; i < 4; ++i)
#pragma unroll
    for (int j = 0; j < 4; ++j)
      s[i][j] = __builtin_amdgcn_mfma_f32_16x16x32_bf16(qf[i], kf[j], s[i][j], 0, 0, 0);

  const float scale = 0.17677669529663687f;
#pragma unroll
  for (int i = 0; i < 4; ++i)
#pragma unroll
    for (int r = 0; r < 4; ++r) {
      int nn = 16 * i + (ln >> 4) * 4 + r;
      float vals[4];
      float vmax = -1e30f;
#pragma unroll
      for (int j = 0; j < 4; ++j) {
        int mm = 16 * j + (ln & 15);
        float x = s[i][j][r] * scale + bias_lds[wv][nn - mm + 63] + mask_lds[nn * 64 + mm];
        vals[j] = x;
        vmax = fmaxf(vmax, x);
      }
#pragma unroll
      for (int d = 1; d < 16; d <<= 1) vmax = fmaxf(vmax, __shfl_xor(vmax, d, 64));
      float sum = 0.f;
#pragma unroll
      for (int j = 0; j < 4; ++j) {
        float p = __expf(vals[j] - vmax);
        vals[j] = p;
        sum += p;
      }
#pragma unroll
      for (int d = 1; d < 16; d <<= 1) sum += __shfl_xor(sum, d, 64);
      float rsv = 1.0f / sum;
#pragma unroll
      for (int j = 0; j < 4; ++j)
        p_lds[wv][nn][16 * j + (ln & 15)] = f2bf(vals[j] * rsv);
    }

  const short* vg = qb + 1024;
  f32x4 o[4][2] = {};
#pragma unroll
  for (int kk = 0; kk < 2; ++kk) {
    s16x8 pa[4];
#pragma unroll
    for (int i2 = 0; i2 < 4; ++i2)
      pa[i2] = *(const s16x8*)&p_lds[wv][16 * i2 + (ln & 15)][kk * 32 + (ln >> 4) * 8];
#pragma unroll
    for (int j2 = 0; j2 < 2; ++j2) {
      s16x8 vf;
#pragma unroll
      for (int jj = 0; jj < 8; ++jj)
        vf[jj] = vg[(size_t)(kk * 32 + (ln >> 4) * 8 + jj) * 1536 + 16 * j2 + (ln & 15)];
#pragma unroll
      for (int i2 = 0; i2 < 4; ++i2)
        o[i2][j2] = __builtin_amdgcn_mfma_f32_16x16x32_bf16(pa[i2], vf, o[i2][j2], 0, 0, 0);
    }
  }

#pragma unroll
  for (int i2 = 0; i2 < 4; ++i2)
#pragma unroll
    for (int j2 = 0; j2 < 2; ++j2)
#pragma unroll
      for (int r = 0; r < 4; ++r) {
        int n = 16 * i2 + (ln >> 4) * 4 + r;
        int d = 16 * j2 + (ln & 15);
        int rr = h * 64 + (b >> 4);
        int ss = (b & 15) * 4 + (n >> 4);
        int cc = (n & 15) * 32 + d;
        Y[((size_t)rr * 64 + ss) * 512 + cc] = f2bf(o[i2][j2][r]);
      }
}

extern "C" void kernel_launch(void* const* d_in, const int* in_sizes, int n_in,
                              void* d_out, int out_size, void* d_ws, size_t ws_size,
                              hipStream_t stream) {
  const float* x      = (const float*)d_in[0];
  const float* mask   = (const float*)d_in[1];
  const float* qkv_w  = (const float*)d_in[2];
  const float* qkv_b  = (const float*)d_in[3];
  const float* proj_w = (const float*)d_in[4];
  const float* proj_b = (const float*)d_in[5];
  const float* btab   = (const float*)d_in[6];
  float* out = (float*)d_out;

  char* w = (char*)d_ws;
  short* qkv_ws = (short*)w;                                             // 192 MiB
  short* xbf    = (short*)(w + (size_t)65536 * 1536 * 2);                // 64 MiB
  short* Y      = xbf;                                                   // reuse after GEMM1
  short* wT     = (short*)(w + (size_t)65536 * 1536 * 2 + (size_t)65536 * 512 * 2);
  short* projT  = wT + 1536 * 512;

  k_cast_bf16<<<16384, 256, 0, stream>>>(x, xbf, 33554432 / 8);
  k_transpose_cast<<<(1536 * 512 + 255) / 256, 256, 0, stream>>>(qkv_w, wT, 512, 1536);
  k_transpose_cast<<<(512 * 512 + 255) / 256, 256, 0, stream>>>(proj_w, projT, 512, 512);
  k_gemm256<false><<<1536, 512, 0, stream>>>(xbf, wT, qkv_b, qkv_ws, 65536, 1536, 512, 6);
  k_attn<<<dim3(1024, 4), 256, 0, stream>>>(qkv_ws, mask, btab, Y);
  k_gemm256<true><<<512, 512, 0, stream>>>(Y, projT, proj_b, out, 65536, 512, 512, 2);
}